// Round 2
// 178.065 us; speedup vs baseline: 1.0595x; 1.0595x over previous
//
#include <hip/hip_runtime.h>

// AtlasAttention, fully fused pipeline:
//   gemm1_poly : q = Xb @ Wqb^T (bf16 MFMA), epilogue emits poly features
//                P[98304][192] bf16  (oct1|oct2|oct3; oct0 folded into b1_eff)
//   gemm23     : per 128-row block: H-slice (128x128) = relu(P @ W1^T + b1e)
//                kept in LDS, immediately consumed by out += H @ W2^T.
//                No H round-trip through HBM.
//
// ws layout (bytes):
//   Xb   @ 0          : 8192*768 bf16   = 12,582,912
//   Wqb  @ 12,582,912 : 768*768  bf16^T = 1,179,648   (Wqb[n][k])
//   W1b  @ 13,762,560 : 512*256  bf16^T = 262,144     (W1b[n][k], k=0..255)
//   W2b  @ 14,024,704 : 64*512   bf16^T = 65,536      (W2b[m][k])
//   b1e  @ 14,090,240 : 512 f32         = 2,048       (b1 + c0*sum_{k<64} W1[k][:])
//   P    @ 14,092,288 : 98304*192 bf16  = 37,748,736  -> ends 51,841,024
//   (old session's chunked GEMM2 proved ws_size >= 114.7 MB, so this fits)

typedef unsigned short u16;
typedef __attribute__((ext_vector_type(8))) short short8;
typedef __attribute__((ext_vector_type(4))) float f32x4;
typedef __attribute__((ext_vector_type(4))) u16 u16x4;

__device__ __forceinline__ u16 f2bf(float f) {
    unsigned u = __builtin_bit_cast(unsigned, f);
    u += 0x7FFFu + ((u >> 16) & 1u);   // RNE
    return (u16)(u >> 16);
}

__device__ __forceinline__ unsigned cvtpk_bf16(float lo, float hi) {
    unsigned r;
    asm("v_cvt_pk_bf16_f32 %0, %1, %2" : "=v"(r) : "v"(lo), "v"(hi));
    return r;
}

__device__ __forceinline__ void gl2lds16(const void* g, void* l) {
    __builtin_amdgcn_global_load_lds(
        (const __attribute__((address_space(1))) unsigned int*)g,
        (__attribute__((address_space(3))) unsigned int*)l, 16, 0, 0);
}

// ---------------- conversion kernels ----------------

__global__ __launch_bounds__(256) void cast_f32_bf16(const float* __restrict__ in,
                                                     u16* __restrict__ out, int n4) {
    int i = blockIdx.x * 256 + threadIdx.x;
    if (i < n4) {
        float4 v = reinterpret_cast<const float4*>(in)[i];
        u16x4 o = {f2bf(v.x), f2bf(v.y), f2bf(v.z), f2bf(v.w)};
        reinterpret_cast<u16x4*>(out)[i] = o;
    }
}

// in: [R][Cin] fp32; out: [C][R] bf16 (first C cols of in). grid (C/32, R/32), block (32,8).
__global__ __launch_bounds__(256) void transpose_cast(const float* __restrict__ in,
                                                      u16* __restrict__ out,
                                                      int R, int Cin) {
    __shared__ float t[32][33];
    const int c0 = blockIdx.x * 32, r0 = blockIdx.y * 32;
    const int tx = threadIdx.x, ty = threadIdx.y;
    #pragma unroll
    for (int j = 0; j < 32; j += 8)
        t[ty + j][tx] = in[(size_t)(r0 + ty + j) * Cin + c0 + tx];
    __syncthreads();
    #pragma unroll
    for (int j = 0; j < 32; j += 8)
        out[(size_t)(c0 + ty + j) * R + r0 + tx] = f2bf(t[tx][ty + j]);
}

// b1e[n] = b1[n] + c0 * sum_{k<64} W1[k][n].  grid 2 x 256.
__global__ __launch_bounds__(256) void make_b1eff(const float* __restrict__ W1,
                                                  const float* __restrict__ b1,
                                                  const float* __restrict__ coeffs,
                                                  float* __restrict__ b1e) {
    const int n = blockIdx.x * 256 + threadIdx.x;   // 0..511
    float s = 0.f;
    #pragma unroll 8
    for (int k = 0; k < 64; ++k) s += W1[k * 512 + n];
    b1e[n] = b1[n] + coeffs[0] * s;
}

// ---------------- GEMM1 + poly epilogue ----------------
// C[8192][768] = A[8192][768] @ B^T[768][768]; epilogue writes
// P[(row*12 + col>>6)][192]: cols [0,64)=c1*x, [64,128)=c2*x^2, [128,192)=c3*x^3,
// x = clip(q, -10, 10).  grid (64, 6), 256 threads (4 waves, 64x64 wave tiles).

__global__ __launch_bounds__(256)
void gemm1_poly(const u16* __restrict__ A, const u16* __restrict__ B,
                const float* __restrict__ coeffs, u16* __restrict__ P)
{
    __shared__ u16 As[128 * 32];
    __shared__ u16 Bs[128 * 32];

    const int tid = threadIdx.x;
    const int w = tid >> 6, lane = tid & 63;
    const int lrow = lane >> 2, lslot = lane & 3;
    const int m16 = lane & 15, quad = lane >> 4;
    const int bm = blockIdx.x * 128, bn = blockIdx.y * 128;
    const int wr = (w & 1) * 64, wc = (w >> 1) * 64;

    const float c1 = coeffs[1], c2 = coeffs[2], c3 = coeffs[3];

    f32x4 acc[4][4];
    #pragma unroll
    for (int i = 0; i < 4; ++i)
        #pragma unroll
        for (int j = 0; j < 4; ++j)
            acc[i][j] = (f32x4){0.f, 0.f, 0.f, 0.f};

    for (int k0 = 0; k0 < 768; k0 += 32) {
        #pragma unroll
        for (int i = 0; i < 2; ++i) {
            const int row = (w * 2 + i) * 16 + lrow;
            const int cc = lslot ^ ((row >> 2) & 3);
            gl2lds16(A + (size_t)(bm + row) * 768 + k0 + cc * 8, &As[row * 32 + lslot * 8]);
            gl2lds16(B + (size_t)(bn + row) * 768 + k0 + cc * 8, &Bs[row * 32 + lslot * 8]);
        }
        __syncthreads();

        short8 af[4], bf[4];
        #pragma unroll
        for (int i = 0; i < 4; ++i) {
            const int row = wr + i * 16 + m16;
            const int s = quad ^ ((row >> 2) & 3);
            af[i] = *reinterpret_cast<const short8*>(&As[row * 32 + s * 8]);
        }
        #pragma unroll
        for (int j = 0; j < 4; ++j) {
            const int row = wc + j * 16 + m16;
            const int s = quad ^ ((row >> 2) & 3);
            bf[j] = *reinterpret_cast<const short8*>(&Bs[row * 32 + s * 8]);
        }
        #pragma unroll
        for (int i = 0; i < 4; ++i)
            #pragma unroll
            for (int j = 0; j < 4; ++j)
                acc[i][j] = __builtin_amdgcn_mfma_f32_16x16x32_bf16(af[i], bf[j], acc[i][j], 0, 0, 0);
        __syncthreads();
    }

    // poly epilogue (each 64-wide wave tile maps to exactly one head)
    #pragma unroll
    for (int j = 0; j < 4; ++j) {
        const int col = bn + wc + j * 16 + m16;
        const int h = col >> 6, d = col & 63;
        #pragma unroll
        for (int i = 0; i < 4; ++i) {
            #pragma unroll
            for (int r = 0; r < 4; ++r) {
                const int row = bm + wr + i * 16 + quad * 4 + r;
                u16* pp = P + ((size_t)row * 12 + h) * 192 + d;
                float x = fminf(fmaxf(acc[i][j][r], -10.f), 10.f);
                const float x2 = x * x;
                const unsigned p12 = cvtpk_bf16(c1 * x, c2 * x2);  // lo=c1*x, hi=c2*x^2
                const unsigned p3  = cvtpk_bf16(c3 * x2 * x, 0.f);
                pp[0]   = (u16)p12;
                pp[64]  = (u16)(p12 >> 16);
                pp[128] = (u16)p3;
            }
        }
    }
}

// ---------------- fused GEMM2+GEMM3 ----------------
// Per block (256 thr, 4 waves): 128 token-rows.
// accO[128][64] held in regs across 4 slices of mem_hid:
//   slice s: accH[nH 128][tok 128] = W1slice @ P^T  (transposed so the drain to
//            LDS is k-contiguous); drain = bf16(relu(accH + b1e)) -> Hs (swizzled);
//            accO += Hs @ W2slice^T.
__global__ __launch_bounds__(256)
void gemm23(const u16* __restrict__ P, const u16* __restrict__ W1t,
            const float* __restrict__ b1e, const u16* __restrict__ W2t,
            const float* __restrict__ b2, float* __restrict__ out)
{
    __shared__ u16 As[128 * 32];      // GEMM2: W1 chunk (nH-major)   | GEMM3: W2 chunks 0,1
    __shared__ u16 Bs[128 * 32];      // GEMM2: poly chunk (tok-major)| GEMM3: W2 chunks 2,3
    __shared__ u16 Hs[4][128 * 32];   // H slice, token-major, per-32k swizzled slots

    const int tid = threadIdx.x;
    const int w = tid >> 6, lane = tid & 63;
    const int lrow = lane >> 2, lslot = lane & 3;
    const int m16 = lane & 15, quad = lane >> 4;
    const size_t r0 = (size_t)blockIdx.x * 128;
    const int w0 = w & 1, w1 = w >> 1;

    f32x4 accO[4][2];
    #pragma unroll
    for (int i = 0; i < 4; ++i)
        #pragma unroll
        for (int j = 0; j < 2; ++j)
            accO[i][j] = (f32x4){0.f, 0.f, 0.f, 0.f};

    #pragma unroll 1
    for (int s = 0; s < 4; ++s) {
        // ---- GEMM2^T slice: accH[i][j], rows=nH (W1), cols=token (poly), K=192 ----
        f32x4 accH[4][4];
        #pragma unroll
        for (int i = 0; i < 4; ++i)
            #pragma unroll
            for (int j = 0; j < 4; ++j)
                accH[i][j] = (f32x4){0.f, 0.f, 0.f, 0.f};

        for (int c = 0; c < 6; ++c) {
            #pragma unroll
            for (int i = 0; i < 2; ++i) {
                const int row = (w * 2 + i) * 16 + lrow;
                const int cc = lslot ^ ((row >> 2) & 3);
                gl2lds16(W1t + (size_t)(s * 128 + row) * 256 + 64 + c * 32 + cc * 8,
                         &As[row * 32 + lslot * 8]);
                gl2lds16(P + (r0 + row) * 192 + c * 32 + cc * 8,
                         &Bs[row * 32 + lslot * 8]);
            }
            __syncthreads();

            short8 af[4], bf[4];
            #pragma unroll
            for (int i = 0; i < 4; ++i) {
                const int row = w0 * 64 + i * 16 + m16;          // nH local
                const int ss = quad ^ ((row >> 2) & 3);
                af[i] = *reinterpret_cast<const short8*>(&As[row * 32 + ss * 8]);
            }
            #pragma unroll
            for (int j = 0; j < 4; ++j) {
                const int row = w1 * 64 + j * 16 + m16;          // token local
                const int ss = quad ^ ((row >> 2) & 3);
                bf[j] = *reinterpret_cast<const short8*>(&Bs[row * 32 + ss * 8]);
            }
            #pragma unroll
            for (int i = 0; i < 4; ++i)
                #pragma unroll
                for (int j = 0; j < 4; ++j)
                    accH[i][j] = __builtin_amdgcn_mfma_f32_16x16x32_bf16(af[i], bf[j], accH[i][j], 0, 0, 0);
            __syncthreads();
        }

        // ---- drain: Hs[token][nH] = bf16(relu(accH + b1e)); k-contiguous b64 writes ----
        #pragma unroll
        for (int i = 0; i < 4; ++i) {
            const int lb = w0 * 64 + i * 16 + quad * 4;          // nH local base (4 consecutive)
            const f32x4 bv = *reinterpret_cast<const f32x4*>(&b1e[s * 128 + lb]);
            const int hc = lb >> 5;                              // Hs chunk (32-wide k group)
            #pragma unroll
            for (int j = 0; j < 4; ++j) {
                const int tc = w1 * 64 + j * 16 + m16;           // token local
                const float h0 = fmaxf(accH[i][j][0] + bv[0], 0.f);
                const float h1 = fmaxf(accH[i][j][1] + bv[1], 0.f);
                const float h2 = fmaxf(accH[i][j][2] + bv[2], 0.f);
                const float h3 = fmaxf(accH[i][j][3] + bv[3], 0.f);
                uint2 v;
                v.x = cvtpk_bf16(h0, h1);
                v.y = cvtpk_bf16(h2, h3);
                const int sl = ((lb >> 3) & 3) ^ ((tc >> 2) & 3);
                *reinterpret_cast<uint2*>(&Hs[hc][tc * 32 + sl * 8 + (lb & 7)]) = v;
            }
        }

        // ---- stage full W2 slice (64 rows x 128 k, 4 chunks) into As/Bs; chunk = wave ----
        {
            u16* dst = (w < 2) ? As : Bs;
            #pragma unroll
            for (int i = 0; i < 4; ++i) {
                const int row = i * 16 + lrow;                   // 0..63 (out col m)
                const int cc = lslot ^ ((row >> 2) & 3);
                gl2lds16(W2t + (size_t)row * 512 + s * 128 + w * 32 + cc * 8,
                         dst + (w & 1) * 2048 + row * 32 + lslot * 8);
            }
        }
        __syncthreads();

        // ---- GEMM3 partial: accO += Hs @ W2slice^T (4 chunks, no inner barriers) ----
        #pragma unroll
        for (int c = 0; c < 4; ++c) {
            short8 a3[4], b3[2];
            #pragma unroll
            for (int i = 0; i < 4; ++i) {
                const int tr = w0 * 64 + i * 16 + m16;           // token local
                const int ss = quad ^ ((tr >> 2) & 3);
                a3[i] = *reinterpret_cast<const short8*>(&Hs[c][tr * 32 + ss * 8]);
            }
            const u16* wsrc = ((c < 2) ? (const u16*)As : (const u16*)Bs) + (c & 1) * 2048;
            #pragma unroll
            for (int j = 0; j < 2; ++j) {
                const int rowb = w1 * 32 + j * 16 + m16;         // out col m
                const int ss = quad ^ ((rowb >> 2) & 3);
                b3[j] = *reinterpret_cast<const short8*>(wsrc + rowb * 32 + ss * 8);
            }
            #pragma unroll
            for (int i = 0; i < 4; ++i)
                #pragma unroll
                for (int j = 0; j < 2; ++j)
                    accO[i][j] = __builtin_amdgcn_mfma_f32_16x16x32_bf16(a3[i], b3[j], accO[i][j], 0, 0, 0);
        }
        __syncthreads();   // before next slice overwrites As/Bs/Hs
    }

    // ---- epilogue: out[r0+row][col] = accO + b2 ----
    #pragma unroll
    for (int j = 0; j < 2; ++j) {
        const int col = w1 * 32 + j * 16 + m16;
        const float bv = b2[col];
        #pragma unroll
        for (int i = 0; i < 4; ++i) {
            #pragma unroll
            for (int r = 0; r < 4; ++r) {
                const int row = w0 * 64 + i * 16 + quad * 4 + r;
                out[(r0 + row) * 64 + col] = accO[i][j][r] + bv;
            }
        }
    }
}

// ---------------- host ----------------

extern "C" void kernel_launch(void* const* d_in, const int* in_sizes, int n_in,
                              void* d_out, int out_size, void* d_ws, size_t ws_size,
                              hipStream_t stream) {
    const float* X      = (const float*)d_in[0];
    const float* Wq     = (const float*)d_in[1];
    const float* coeffs = (const float*)d_in[2];
    const float* W1     = (const float*)d_in[3];
    const float* b1     = (const float*)d_in[4];
    const float* W2     = (const float*)d_in[5];
    const float* b2     = (const float*)d_in[6];

    char* ws = (char*)d_ws;
    u16*   Xb  = (u16*)(ws);
    u16*   Wqb = (u16*)(ws + 12582912);
    u16*   W1b = (u16*)(ws + 13762560);
    u16*   W2b = (u16*)(ws + 14024704);
    float* b1e = (float*)(ws + 14090240);
    u16*   P   = (u16*)(ws + 14092288);

    cast_f32_bf16<<<6144, 256, 0, stream>>>(X, Xb, 8192 * 768 / 4);
    transpose_cast<<<dim3(24, 24), dim3(32, 8), 0, stream>>>(Wq, Wqb, 768, 768);
    transpose_cast<<<dim3(16, 8),  dim3(32, 8), 0, stream>>>(W1, W1b, 256, 512);
    transpose_cast<<<dim3(2, 16),  dim3(32, 8), 0, stream>>>(W2, W2b, 512, 256);
    make_b1eff<<<2, 256, 0, stream>>>(W1, b1, coeffs, b1e);

    // GEMM1 + poly epilogue: P = poly(clip(Xb @ Wqb^T)) in bf16, K folded 256->192
    gemm1_poly<<<dim3(64, 6), 256, 0, stream>>>(Xb, Wqb, coeffs, P);

    // fused GEMM2+GEMM3: out = (relu(P @ W1[64:]^T + b1e)) @ W2^T + b2
    gemm23<<<dim3(768), 256, 0, stream>>>(P, W1b, b1e, W2b, b2, (float*)d_out);
}